// Round 1
// baseline (196.880 us; speedup 1.0000x reference)
//
#include <hip/hip_runtime.h>

// UpFirDn 2x downsample: depthwise 4x4 FIR (separable binomial), stride 2,
// pad (1,1). x: (16,512,64,64) f32 -> out: (16,512,32,32) f32.
//
// One block per (n,c) image, 256 threads. Separable two-pass through LDS.
//
// Stage 1 (dense loads): lane t loads float4 #(i*256+t) -> each dwordx4
//   instruction covers 1KB contiguous (16 cache lines, vs 64 lines/inst in
//   the previous row-quarter layout). Horizontal halo via __shfl_up/down
//   within the wave; c4==0/15 lanes (the row edges) forced to zero-pad.
//   h[row][2c],h[2c+1] written as float2 to LDS (pitch 36 -> 16B-aligned
//   rows, bank stagger 4).
// Stage 2: vertical filter. h rows -1 and 64 are zeroed LDS rows (0 and 65),
//   so the filter is branchless: 4x ds_read_b128 + 16 FMA + dwordx4 store.

#define IH 64
#define IW 64
#define OHN 32
#define OWN 32
#define HP 36      // hbuf pitch (floats): 144B rows -> 16B aligned, %32==4 bank stagger
#define HROWS 66   // h rows -1..64 stored shifted +1; rows 0 and 65 are zero

__global__ __launch_bounds__(256) void upfirdn_down2_kernel(
    const float* __restrict__ x, const float* __restrict__ kk,
    float* __restrict__ out)
{
    __shared__ float hbuf[HROWS * HP];  // 66*36*4 = 9504 B

    const int t = threadIdx.x;
    const int img = blockIdx.x;
    const float* __restrict__ xi = x + (size_t)img * (IH * IW);
    float* __restrict__ oi = out + (size_t)img * (OHN * OWN);

    // zero the vertical halo rows: h[-1] (row 0) and h[64] (row 65)
    if (t < HP) hbuf[t] = 0.0f;
    else if (t < 2 * HP) hbuf[(HROWS - 1) * HP + (t - HP)] = 0.0f;

    // --- separable weights from the (flipped) 4x4 kernel ------------------
    // W[i][j] = kk[3-i][3-j]; kh[j] = col sums of flipped, kv[i] = row sums.
    const float4 k0 = ((const float4*)kk)[0];
    const float4 k1 = ((const float4*)kk)[1];
    const float4 k2 = ((const float4*)kk)[2];
    const float4 k3 = ((const float4*)kk)[3];
    const float kh0 = k0.w + k1.w + k2.w + k3.w;
    const float kh1 = k0.z + k1.z + k2.z + k3.z;
    const float kh2 = k0.y + k1.y + k2.y + k3.y;
    const float kh3 = k0.x + k1.x + k2.x + k3.x;
    const float kv0 = k3.x + k3.y + k3.z + k3.w;
    const float kv1 = k2.x + k2.y + k2.z + k2.w;
    const float kv2 = k1.x + k1.y + k1.z + k1.w;
    const float kv3 = k0.x + k0.y + k0.z + k0.w;

    // --- stage 1: dense float4 loads + shuffle halo + horizontal filter ---
    // float4 #f: row = f>>4, col4 = f&15 (owns x cols 4c..4c+3).
    // h[2c]   = kh0*x[4c-1] + kh1*x[4c]   + kh2*x[4c+1] + kh3*x[4c+2]
    // h[2c+1] = kh0*x[4c+1] + kh1*x[4c+2] + kh2*x[4c+3] + kh3*x[4c+4]
    const int c4 = t & 15;
    const int rb = t >> 4;
#pragma unroll
    for (int i = 0; i < 4; ++i) {
        const float4 v = ((const float4*)xi)[i * 256 + t];
        const int row = i * 16 + rb;
        float lft = __shfl_up(v.w, 1);    // x[4c-1] from lane t-1
        float rgt = __shfl_down(v.x, 1);  // x[4c+4] from lane t+1
        if (c4 == 0)  lft = 0.0f;         // left zero-pad (and lane-0 safety)
        if (c4 == 15) rgt = 0.0f;         // right zero-pad (and lane-63 safety)
        const float h0 = kh0 * lft + kh1 * v.x + kh2 * v.y + kh3 * v.z;
        const float h1 = kh0 * v.y + kh1 * v.z + kh2 * v.w + kh3 * rgt;
        *(float2*)&hbuf[(row + 1) * HP + 2 * c4] = make_float2(h0, h1);
    }
    __syncthreads();

    // --- stage 2: vertical filter, branchless, 4-wide per thread ----------
    // thread t: oh = t>>3, ow = 4*(t&7)..+3. out row oh needs h rows
    // 2oh-1..2oh+2 = stored rows 2oh..2oh+3 (zero rows cover the halo).
    {
        const int ow4 = t & 7;
        const int oh = t >> 3;
        const float* hb = &hbuf[2 * oh * HP + 4 * ow4];
        const float4 r0 = *(const float4*)(hb);
        const float4 r1 = *(const float4*)(hb + HP);
        const float4 r2 = *(const float4*)(hb + 2 * HP);
        const float4 r3 = *(const float4*)(hb + 3 * HP);
        float4 o;
        o.x = kv0 * r0.x + kv1 * r1.x + kv2 * r2.x + kv3 * r3.x;
        o.y = kv0 * r0.y + kv1 * r1.y + kv2 * r2.y + kv3 * r3.y;
        o.z = kv0 * r0.z + kv1 * r1.z + kv2 * r2.z + kv3 * r3.z;
        o.w = kv0 * r0.w + kv1 * r1.w + kv2 * r2.w + kv3 * r3.w;
        *(float4*)&oi[oh * OWN + 4 * ow4] = o;
    }
}

extern "C" void kernel_launch(void* const* d_in, const int* in_sizes, int n_in,
                              void* d_out, int out_size, void* d_ws, size_t ws_size,
                              hipStream_t stream) {
    const float* x = (const float*)d_in[0];
    const float* k = (const float*)d_in[1];
    float* out = (float*)d_out;
    const int n_img = in_sizes[0] / (IH * IW);  // 16*512 = 8192
    upfirdn_down2_kernel<<<n_img, 256, 0, stream>>>(x, k, out);
}